// Round 12
// baseline (191.888 us; speedup 1.0000x reference)
//
#include <hip/hip_runtime.h>
#include <hip/hip_bf16.h>
#include <stdint.h>
#include <utility>

// ---------------------------------------------------------------------------
// E=64 H=64 PRE1=512 BNK=1024 S=256 P=16 B=4096. Attention branch dead
// (softmax over size-1 axis == 1). Decomposition (rel is rank-2):
//   Z1[s,i,j,k] = rx*MX[k] + ry*MY[k] + HH[16s+j][k];  Y1 = relu(Z1)
//   out = maxpool_j relu(bn2(Y1 @ Wp2))
// v22: WAVES/SIMD pivot -- the only untested axis. All Phase-C variants
//   (v13/14/17/18/21) ran exactly 2 waves/SIMD (240 regs/wave + 144KB LDS
//   force it) and ALL pin at ~1360cyc/wave-step with 256cyc MFMA (~40%).
//   Hypothesis: per-wave serial {~850cyc non-MFMA, 256cyc MFMA} segments
//   re-synchronize across the 2 streams (shared LDS/L2 stalls) -> pipe
//   busy 512/1360. 4 streams/SIMD: 4x256/1360 ~ 75% potential.
//   v22: 1024-thr WG = 16 waves (4/SIMD). Wave = 2rt x 2ct:
//   acc[2][2]=64 AGPR + A ring-2 (16) + B ring-2 (16) + misc ~ 110-120
//   <= 128 (per-SIMD pool 512 regs / 4 waves; m69). launch_bounds(1024,4).
//   Per-CU traffic = v14/v17 (32 A-b128/kstep; B 2MB/block, priced ~0).
//   Continuous 64-step static schedule; ring slot = G&1 (no WAR -- v20
//   lesson); waits vmcnt(2) lgkm(2) steady, vmcnt(10) at pass boundary
//   (B32 precedes 8 epi vm-ops in issue order), 0/0 tail; epilogues
//   outside folds (v16 lesson); cached B (v17); no setprio (v21 null).
//   Falsifier: 68-75us + clean canaries => ceiling verdict next round.
//   LDS = Y1 128K + HH 16K = 144 KB, 1 WG/CU, 16 waves.
// ---------------------------------------------------------------------------

typedef __bf16 bf16x8 __attribute__((ext_vector_type(8)));
typedef __bf16 bf16x2 __attribute__((ext_vector_type(2)));
typedef float  f32x4  __attribute__((ext_vector_type(4)));
typedef float  f32x2  __attribute__((ext_vector_type(2)));
typedef float  f32x16 __attribute__((ext_vector_type(16)));

// workspace layout (bytes)
#define BP2_OFF 0u          // packed Wp2, 32x32x16 B-frags: [kstep(32)][ct(32)][l(64)]*16B = 1 MB
#define BP1_OFF 1048576u    // packed W1b (Wp1 rows 64..127): [nt(32)][kb(2)][l]*16B = 64 KB
#define MX_OFF  1114112u    // 512 f32
#define MY_OFF  1116160u
#define CB_OFF  1118208u
#define SH_OFF  1120256u
#define A2_OFF  1122304u    // 1024 f32
#define C2_OFF  1126400u

// mm4 LDS layout (bytes)
#define Y1_LDS  0           // bf16 [128 r][512 k], row stride 1024 B, off = ((c16^(r&7))<<4)
#define HH_LDS  131072      // bf16 [16 j][512 k], row stride 1024 B
#define LDS_SZ  147456      // 144 KB

#define WAITCNT(S) do { asm volatile("s_waitcnt " S ::: "memory"); \
                        __builtin_amdgcn_sched_barrier(0); } while (0)

__device__ __forceinline__ unsigned short f2bf(float f) {
    union { float f; unsigned u; } c; c.f = f;
    unsigned u = c.u;
    return (unsigned short)((u + 0x7fffu + ((u >> 16) & 1u)) >> 16);
}
__device__ __forceinline__ float bfbits2f(unsigned hi) {
    union { unsigned u; float f; } c; c.u = hi; return c.f;
}
__device__ __forceinline__ unsigned pk_bf16(float a, float b) {
#if __has_builtin(__builtin_amdgcn_cvt_pk_bf16_f32)
    bf16x2 p = __builtin_amdgcn_cvt_pk_bf16_f32(a, b);
    union { bf16x2 v; unsigned u; } c; c.v = p; return c.u;
#else
    return (unsigned)f2bf(a) | ((unsigned)f2bf(b) << 16);
#endif
}
// Y1 address: row r (0..127), 16-byte chunk c16 (0..63).
__device__ __forceinline__ int y1off(int r, int c16) {
    return r * 1024 + ((c16 ^ (r & 7)) << 4);
}

// static_for: fold over integral_constants (C++17)
template<class F, int... Is>
__device__ __forceinline__ void sf_impl(F& f, std::integer_sequence<int, Is...>) {
    (f(std::integral_constant<int, Is>{}), ...);
}
template<int N, class F>
__device__ __forceinline__ void static_for(F&& f) {
    sf_impl(f, std::make_integer_sequence<int, N>{});
}

// ---------------------------------------------------------------------------
// prep_pack: blocks 0..255 pack Wp2 into 32x32x16 B-frag layout
// ([kstep][ct][l]); 256..271 pack W1b (16x16x32 layout for Phase A);
// 272..279 fold k-consts (64 k each, 4-way e-split + LDS reduce);
// 280..283 fold A2/C2. All global reads coalesced. UNCHANGED.
// 32x32x16 B-frag: lane l holds B[k=kstep*16+(l>>5)*8+j][n=ct*32+(l&31)].
// 16x16x32 B-frag: lane l holds B[k=kb*32+(l>>4)*8+j][n=nt*16+(l&15)].
// ---------------------------------------------------------------------------
__global__ __launch_bounds__(256) void prep_pack_kernel(
    const float* __restrict__ Wsp,  const float* __restrict__ bsp,
    const float* __restrict__ Wp1,  const float* __restrict__ bp1,
    const float* __restrict__ gp1,  const float* __restrict__ btp1,
    const float* __restrict__ mp1,  const float* __restrict__ vp1,
    const float* __restrict__ Wp2,  const float* __restrict__ bp2,
    const float* __restrict__ gp2,  const float* __restrict__ btp2,
    const float* __restrict__ mp2,  const float* __restrict__ vp2,
    unsigned char* __restrict__ ws)
{
    __shared__ float tile[32 * 65];
    __shared__ float part[3][4][64];
    const int blk = blockIdx.x, t = threadIdx.x;

    if (blk < 272) {
        const float* src; int ncols, kb, ng;
        if (blk < 256) { kb = blk >> 4; ng = blk & 15; src = Wp2; ncols = 1024; }
        else { int b2 = blk - 256; kb = b2 >> 3; ng = b2 & 7; src = Wp1 + 64 * 512; ncols = 512; }
        const int k0 = kb * 32, n0 = ng * 64;
        #pragma unroll
        for (int it = 0; it < 2; ++it) {
            int c = t + it * 256;
            int r = c >> 4, c4 = c & 15;
            float4 v = *(const float4*)(src + (k0 + r) * ncols + n0 + c4 * 4);
            tile[r * 65 + c4 * 4 + 0] = v.x;
            tile[r * 65 + c4 * 4 + 1] = v.y;
            tile[r * 65 + c4 * 4 + 2] = v.z;
            tile[r * 65 + c4 * 4 + 3] = v.w;
        }
        __syncthreads();
        if (blk < 256) {
            const int l = t & 63, ch = (t >> 6) & 1, kh = t >> 7;
            const int nl = ch * 32 + (l & 31);
            const int kl = kh * 16 + ((l >> 5) & 1) * 8;
            uint4 o;
            o.x = pk_bf16(tile[(kl + 0) * 65 + nl], tile[(kl + 1) * 65 + nl]);
            o.y = pk_bf16(tile[(kl + 2) * 65 + nl], tile[(kl + 3) * 65 + nl]);
            o.z = pk_bf16(tile[(kl + 4) * 65 + nl], tile[(kl + 5) * 65 + nl]);
            o.w = pk_bf16(tile[(kl + 6) * 65 + nl], tile[(kl + 7) * 65 + nl]);
            const int kstep = kb * 2 + kh, ct = ng * 2 + ch;
            ((uint4*)(ws + BP2_OFF))[(kstep * 32 + ct) * 64 + l] = o;
        } else {
            int ntl = t >> 6, l = t & 63;
            int nl = ntl * 16 + (l & 15), kl = (l >> 4) * 8;
            uint4 o;
            o.x = pk_bf16(tile[(kl + 0) * 65 + nl], tile[(kl + 1) * 65 + nl]);
            o.y = pk_bf16(tile[(kl + 2) * 65 + nl], tile[(kl + 3) * 65 + nl]);
            o.z = pk_bf16(tile[(kl + 4) * 65 + nl], tile[(kl + 5) * 65 + nl]);
            o.w = pk_bf16(tile[(kl + 6) * 65 + nl], tile[(kl + 7) * 65 + nl]);
            ((uint4*)(ws + BP1_OFF))[((ng * 4 + ntl) * 2 + kb) * 64 + l] = o;
        }
    } else if (blk < 280) {
        const int kk = t & 63, eq = t >> 6;
        const int k = (blk - 272) * 64 + kk;
        float mx = 0.f, my = 0.f, cb = 0.f;
        #pragma unroll
        for (int e2 = 0; e2 < 16; ++e2) {
            int e = eq * 16 + e2;
            float wv = Wp1[e * 512 + k];
            mx = fmaf(Wsp[e],      wv, mx);
            my = fmaf(Wsp[64 + e], wv, my);
            cb = fmaf(bsp[e],      wv, cb);
        }
        part[0][eq][kk] = mx; part[1][eq][kk] = my; part[2][eq][kk] = cb;
        __syncthreads();
        if (t < 64) {
            const int k2 = (blk - 272) * 64 + t;
            float mxs = part[0][0][t] + part[0][1][t] + part[0][2][t] + part[0][3][t];
            float mys = part[1][0][t] + part[1][1][t] + part[1][2][t] + part[1][3][t];
            float cbs = part[2][0][t] + part[2][1][t] + part[2][2][t] + part[2][3][t];
            float a1 = gp1[k2] * rsqrtf(vp1[k2] + 1e-5f);
            ((float*)(ws + MX_OFF))[k2] = 0.05f * a1 * mxs;
            ((float*)(ws + MY_OFF))[k2] = 0.05f * a1 * mys;
            ((float*)(ws + CB_OFF))[k2] = 0.05f * a1 * cbs + (bp1[k2] - mp1[k2]) * a1 + btp1[k2];
            ((float*)(ws + SH_OFF))[k2] = 0.05f * a1;
        }
    } else {
        int n = (blk - 280) * 256 + t;
        float a = gp2[n] * rsqrtf(vp2[n] + 1e-5f);
        ((float*)(ws + A2_OFF))[n] = a;
        ((float*)(ws + C2_OFF))[n] = btp2[n] + (bp2[n] - mp2[n]) * a;
    }
}

// ---------------------------------------------------------------------------
// mm4 v22: WG = (scene s, i-half ih). 1024 thr = 16 waves (4/SIMD).
// Phase A: HH[16x512] via 4 MFMA/wave (2 coltiles each).
// Phase B: construct Y1[128x512] bf16 (1024 thr x 2 ii).
// Phase C: wave (rg = w>>3, cg = w&7) = 2rt x 2ct, 2 passes; continuous
//   64-step static schedule, A/B ring-2 (slot = G&1), counted waits.
// ---------------------------------------------------------------------------
__global__ __launch_bounds__(1024, 4) void mm4_kernel(
    const float* __restrict__ hst,
    const float* __restrict__ epos,
    const unsigned char* __restrict__ ws,
    float* __restrict__ out)
{
    __shared__ __align__(16) unsigned char smem[LDS_SZ];

    const int s   = blockIdx.x >> 1;     // 256 scenes
    const int ih  = blockIdx.x & 1;      // i-half
    const int tid = threadIdx.x;
    const int w    = tid >> 6;           // 0..15
    const int l    = tid & 63;
    const int quad = l >> 4;
    const int jl   = l & 15;

    // ---- Phase A: HH via MFMA (16x16x32); wave w -> k-cols w*32..+31 ----
    {
        union { unsigned u[4]; bf16x8 v; } afh[2];
        #pragma unroll
        for (int kb = 0; kb < 2; ++kb) {
            const float4* hp = (const float4*)(hst + (s * 16 + jl) * 64 + kb * 32 + quad * 8);
            float4 v0 = hp[0], v1 = hp[1];
            afh[kb].u[0] = pk_bf16(v0.x, v0.y);
            afh[kb].u[1] = pk_bf16(v0.z, v0.w);
            afh[kb].u[2] = pk_bf16(v1.x, v1.y);
            afh[kb].u[3] = pk_bf16(v1.z, v1.w);
        }
        const f32x4 fz = {0.f, 0.f, 0.f, 0.f};
        f32x4 acch[2] = {fz, fz};
        #pragma unroll
        for (int kb = 0; kb < 2; ++kb) {
            #pragma unroll
            for (int ct = 0; ct < 2; ++ct) {
                bf16x8 bfr = *(const bf16x8*)(ws + BP1_OFF + ((((w * 2 + ct) * 2 + kb) * 64 + l) << 4));
                acch[ct] = __builtin_amdgcn_mfma_f32_16x16x32_bf16(afh[kb].v, bfr, acch[ct], 0, 0, 0);
            }
        }
        const float* SHg = (const float*)(ws + SH_OFF);
        const float* CBg = (const float*)(ws + CB_OFF);
        #pragma unroll
        for (int ct = 0; ct < 2; ++ct) {
            int col = (w * 2 + ct) * 16 + jl;        // k index
            float sh = SHg[col], cb = CBg[col];
            #pragma unroll
            for (int reg = 0; reg < 4; ++reg) {
                int j = quad * 4 + reg;
                float hv = fmaf(acch[ct][reg], sh, cb);
                *(unsigned short*)(smem + HH_LDS + j * 1024 + col * 2) = f2bf(hv);
            }
        }
    }
    __syncthreads();

    // ---- Phase B: construct Y1 (bf16, swizzled); chunk = kk*16+kc ----
    {
        const int i4 = tid >> 8;           // 0..3  (2 i each)
        const int j  = (tid >> 4) & 15;
        const int kc = tid & 15;
        float rx[2], ry[2];
        float pjx = epos[s * 32 + j * 2], pjy = epos[s * 32 + j * 2 + 1];
        #pragma unroll
        for (int ii = 0; ii < 2; ++ii) {
            int ig_ = ih * 8 + i4 * 2 + ii;
            rx[ii] = pjx - epos[s * 32 + ig_ * 2];
            ry[ii] = pjy - epos[s * 32 + ig_ * 2 + 1];
        }
        const f32x2 zero2 = {0.f, 0.f};
        #pragma unroll
        for (int kk = 0; kk < 4; ++kk) {
            int c16 = kk * 16 + kc;
            int k = c16 * 8;
            uint4 hh8 = *(const uint4*)(smem + HH_LDS + j * 1024 + k * 2);
            f32x4 mx0 = *(const f32x4*)(ws + MX_OFF + k * 4);
            f32x4 mx1 = *(const f32x4*)(ws + MX_OFF + k * 4 + 16);
            f32x4 my0 = *(const f32x4*)(ws + MY_OFF + k * 4);
            f32x4 my1 = *(const f32x4*)(ws + MY_OFF + k * 4 + 16);
            f32x2 mxp[4] = { {mx0[0],mx0[1]}, {mx0[2],mx0[3]}, {mx1[0],mx1[1]}, {mx1[2],mx1[3]} };
            f32x2 myp[4] = { {my0[0],my0[1]}, {my0[2],my0[3]}, {my1[0],my1[1]}, {my1[2],my1[3]} };
            f32x2 hhp[4];
            hhp[0][0] = bfbits2f(hh8.x << 16); hhp[0][1] = bfbits2f(hh8.x & 0xffff0000u);
            hhp[1][0] = bfbits2f(hh8.y << 16); hhp[1][1] = bfbits2f(hh8.y & 0xffff0000u);
            hhp[2][0] = bfbits2f(hh8.z << 16); hhp[2][1] = bfbits2f(hh8.z & 0xffff0000u);
            hhp[3][0] = bfbits2f(hh8.w << 16); hhp[3][1] = bfbits2f(hh8.w & 0xffff0000u);
            #pragma unroll
            for (int ii = 0; ii < 2; ++ii) {
                f32x2 rx2 = { rx[ii], rx[ii] };
                f32x2 ry2 = { ry[ii], ry[ii] };
                uint4 o;
                unsigned uu[4];
                #pragma unroll
                for (int p = 0; p < 4; ++p) {
                    f32x2 tt = __builtin_elementwise_fma(ry2, myp[p], hhp[p]);
                    tt = __builtin_elementwise_fma(rx2, mxp[p], tt);
                    tt = __builtin_elementwise_max(tt, zero2);
                    uu[p] = pk_bf16(tt[0], tt[1]);
                }
                o.x = uu[0]; o.y = uu[1]; o.z = uu[2]; o.w = uu[3];
                int r = (i4 * 2 + ii) * 16 + j;
                *(uint4*)(smem + Y1_LDS + y1off(r, c16)) = o;
            }
        }
    }
    __syncthreads();

    // ---- Phase C: 32x32x16 GEMM, 16 waves, 2rt x 2ct per wave ----
    {
        const int lane31 = l & 31;           // A-frag m, C col
        const int hi = l >> 5;               // k-half; C row group
        const int sr = lane31 & 7;
        const int rg = w >> 3;               // rowgroup: rowtiles rg*2, rg*2+1
        const int cg = w & 7;                // colgroup: 2 coltiles per pass
        const float* A2 = (const float*)(ws + A2_OFF);
        const float* C2 = (const float*)(ws + C2_OFF);

        // A addr(rr, k) = (av[rr] + (k>>2)*128) ^ ((k&3)<<5)
        int av[2];
        #pragma unroll
        for (int rr = 0; rr < 2; ++rr)
            av[rr] = Y1_LDS + ((rg * 2 + rr) * 32 + lane31) * 1024 + ((hi ^ sr) << 4);

        // B addr(pass, k, c) = bp + pass*16384 + k*32768 + c*1024
        const unsigned char* bp = ws + BP2_OFF + ((cg * 2) << 10) + (l << 4);

        const f32x16 fz16 = {0.f,0.f,0.f,0.f,0.f,0.f,0.f,0.f,
                             0.f,0.f,0.f,0.f,0.f,0.f,0.f,0.f};
        f32x16 acc[2][2];
        bf16x8 ar[2][2];   // A ring-2, slot = G&1: [slot][rr]
        bf16x8 br[2][2];   // B ring-2, slot = G&1: [slot][c]

        #pragma unroll
        for (int rr = 0; rr < 2; ++rr) { acc[rr][0] = fz16; acc[rr][1] = fz16; }

        // epilogue: bn2 + relu, maxpool over j, store fp32. 4 loads + 4 stores.
        // C/D 32x32: col = lane&31, row = (reg&3)+8*(reg>>2)+4*hi (+16 hg=1).
        auto epilogue = [&](int pass) {
            #pragma unroll
            for (int c = 0; c < 2; ++c) {
                const int col = (pass * 16 + cg * 2 + c) * 32 + lane31;
                const float a2 = A2[col], c2 = C2[col];
                #pragma unroll
                for (int rr = 0; rr < 2; ++rr) {
                    float mv[2];
                    #pragma unroll
                    for (int hg = 0; hg < 2; ++hg) {
                        float v0 = fmaxf(fmaf(acc[rr][c][hg * 8 + 0], a2, c2), 0.f);
                        float v1 = fmaxf(fmaf(acc[rr][c][hg * 8 + 1], a2, c2), 0.f);
                        float v2 = fmaxf(fmaf(acc[rr][c][hg * 8 + 2], a2, c2), 0.f);
                        float v3 = fmaxf(fmaf(acc[rr][c][hg * 8 + 3], a2, c2), 0.f);
                        float v4 = fmaxf(fmaf(acc[rr][c][hg * 8 + 4], a2, c2), 0.f);
                        float v5 = fmaxf(fmaf(acc[rr][c][hg * 8 + 5], a2, c2), 0.f);
                        float v6 = fmaxf(fmaf(acc[rr][c][hg * 8 + 6], a2, c2), 0.f);
                        float v7 = fmaxf(fmaf(acc[rr][c][hg * 8 + 7], a2, c2), 0.f);
                        float m = fmaxf(fmaxf(fmaxf(v0, v1), fmaxf(v2, v3)),
                                        fmaxf(fmaxf(v4, v5), fmaxf(v6, v7)));
                        mv[hg] = fmaxf(m, __shfl_xor(m, 32, 64));
                    }
                    const int iloc = (rg * 2 + rr) * 2 + hi;
                    const float vout = hi ? mv[1] : mv[0];
                    const int orow = s * 16 + ih * 8 + iloc;
                    __builtin_nontemporal_store(vout, &out[orow * 1024 + col]);
                }
            }
        };

        // issue loads for global step GN: 2 B (cached) + 2 A ds_reads
        auto issueG = [&](auto Gc) {
            constexpr int GN = decltype(Gc)::value;
            constexpr int pn = GN >> 5, kn = GN & 31, sl = GN & 1;
            const unsigned char* b = bp + (pn * 16384 + kn * 32768);
            br[sl][0] = *(const bf16x8*)(b);
            br[sl][1] = *(const bf16x8*)(b + 1024);
            constexpr int add = (kn >> 2) * 128;
            constexpr int xr  = (kn & 3) << 5;
            #pragma unroll
            for (int rr = 0; rr < 2; ++rr)
                ar[sl][rr] = *(const bf16x8*)(smem + ((av[rr] + add) ^ xr));
        };

        auto stepG = [&](auto Gc) {
            constexpr int G = decltype(Gc)::value;
            if constexpr (G + 1 <= 63)
                issueG(std::integral_constant<int, G + 1>{});
            // waits (in-order vmcnt retire):
            //   steady: B lead-1 -> vmcnt(2); A lead-1 -> lgkmcnt(2).
            //   G=32: order B32(2), epi(4 ld + 4 st), B33(2) -> retire B32
            //         at <= 10 outstanding -> vmcnt(10). A32 drained by
            //         epilogue shfl waits (in-order lgkm).
            //   G=63: full drain.
            if constexpr (G == 32)
                asm volatile("s_waitcnt vmcnt(10) lgkmcnt(2)" ::: "memory");
            else if constexpr (G == 63)
                asm volatile("s_waitcnt vmcnt(0) lgkmcnt(0)" ::: "memory");
            else
                asm volatile("s_waitcnt vmcnt(2) lgkmcnt(2)" ::: "memory");
            __builtin_amdgcn_sched_barrier(0);
            constexpr int sl = G & 1;
            #pragma unroll
            for (int c = 0; c < 2; ++c)
                #pragma unroll
                for (int rr = 0; rr < 2; ++rr)
                    acc[rr][c] = __builtin_amdgcn_mfma_f32_32x32x16_bf16(
                        ar[sl][rr], br[sl][c], acc[rr][c], 0, 0, 0);
        };

        // prologue: G=0's loads
        issueG(std::integral_constant<int, 0>{});

        static_for<32>(stepG);                          // G = 0..31 (pass 0)
        __builtin_amdgcn_sched_barrier(0);
        epilogue(0);
        #pragma unroll
        for (int rr = 0; rr < 2; ++rr) { acc[rr][0] = fz16; acc[rr][1] = fz16; }
        __builtin_amdgcn_sched_barrier(0);
        static_for<32>([&](auto kc) {                   // G = 32..63 (pass 1)
            stepG(std::integral_constant<int, decltype(kc)::value + 32>{});
        });
        __builtin_amdgcn_sched_barrier(0);
        epilogue(1);
    }
}

extern "C" void kernel_launch(void* const* d_in, const int* in_sizes, int n_in,
                              void* d_out, int out_size, void* d_ws, size_t ws_size,
                              hipStream_t stream) {
    const float* hst  = (const float*)d_in[0];
    const float* epos = (const float*)d_in[1];
    const float* Wsp  = (const float*)d_in[4];
    const float* bsp  = (const float*)d_in[5];
    const float* Wp1  = (const float*)d_in[20];
    const float* bp1  = (const float*)d_in[21];
    const float* gp1  = (const float*)d_in[22];
    const float* btp1 = (const float*)d_in[23];
    const float* mp1  = (const float*)d_in[24];
    const float* vp1  = (const float*)d_in[25];
    const float* Wp2  = (const float*)d_in[26];
    const float* bp2  = (const float*)d_in[27];
    const float* gp2  = (const float*)d_in[28];
    const float* btp2 = (const float*)d_in[29];
    const float* mp2  = (const float*)d_in[30];
    const float* vp2  = (const float*)d_in[31];
    unsigned char* ws = (unsigned char*)d_ws;
    float* out = (float*)d_out;

    // 256 (Wp2 pack) + 16 (W1b pack) + 8 (k-consts) + 4 (A2/C2) = 284 blocks
    prep_pack_kernel<<<284, 256, 0, stream>>>(Wsp, bsp, Wp1, bp1, gp1, btp1, mp1, vp1,
                                              Wp2, bp2, gp2, btp2, mp2, vp2, ws);
    // 256 scenes x 2 i-halves, 1024 threads (16 waves, 4/SIMD)
    mm4_kernel<<<512, 1024, 0, stream>>>(hst, epos, ws, out);
}

// Round 13
// 182.964 us; speedup vs baseline: 1.0488x; 1.0488x over previous
//
#include <hip/hip_runtime.h>
#include <hip/hip_bf16.h>
#include <stdint.h>
#include <utility>

// ---------------------------------------------------------------------------
// E=64 H=64 PRE1=512 BNK=1024 S=256 P=16 B=4096. Attention branch dead
// (softmax over size-1 axis == 1). Decomposition (rel is rank-2):
//   Z1[s,i,j,k] = rx*MX[k] + ry*MY[k] + HH[16s+j][k];  Y1 = relu(Z1)
//   out = maxpool_j relu(bn2(Y1 @ Wp2))
// v23: ADDITIVE-TRAFFIC model (fits all 12 rounds: pipes don't overlap;
//   wall = A-LDS/85 + B-TA/~35 + MFMA, = 86k cyc = v14's 72us; explains
//   v15/v17/v22 exactly and why schedule/leads/TLP/phases were all null).
//   Lever: A-amplification = 32/ct_per_wave, bounded by acc<=128 AGPR at
//   2 waves/SIMD. At 1 WAVE/SIMD budget = 512 regs -> acc[4][4] = 256
//   AGPR legal -> wave = 4rt x 4CT -> A-LDS halves (2MB->1MB, 24k->12k).
//   B & MFMA unchanged. Sum 74k -> predict mm5 ~60-67us. TLP loss is free
//   under the model (TLP never helped: v18/v22 nulls).
//   256 thr = 4 waves; regs 256 acc + ar[2][4] + br[2][4] + misc ~ 410
//   < 512, no spill expected. Phase B on 256 thr (8 ii/thread, ~+5k cyc).
//   Waits (in-order retire): steady vmcnt(4) lgkm(4); G=32 vmcnt(28)
//   (B32 + 24 epi vm + B33 in flight; A32 drained by epi shfl waits);
//   G=63 0/0. Epilogues outside folds (v16); cached B (v17); ring slot
//   G&1 (no WAR, v20); no setprio/barrier grafts (v21 null).
//   LDS = Y1 128K + HH 16K = 144 KB, 1 WG/CU, 4 waves (1/SIMD).
// ---------------------------------------------------------------------------

typedef __bf16 bf16x8 __attribute__((ext_vector_type(8)));
typedef __bf16 bf16x2 __attribute__((ext_vector_type(2)));
typedef float  f32x4  __attribute__((ext_vector_type(4)));
typedef float  f32x2  __attribute__((ext_vector_type(2)));
typedef float  f32x16 __attribute__((ext_vector_type(16)));

// workspace layout (bytes)
#define BP2_OFF 0u          // packed Wp2, 32x32x16 B-frags: [kstep(32)][ct(32)][l(64)]*16B = 1 MB
#define BP1_OFF 1048576u    // packed W1b (Wp1 rows 64..127): [nt(32)][kb(2)][l]*16B = 64 KB
#define MX_OFF  1114112u    // 512 f32
#define MY_OFF  1116160u
#define CB_OFF  1118208u
#define SH_OFF  1120256u
#define A2_OFF  1122304u    // 1024 f32
#define C2_OFF  1126400u

// mm5 LDS layout (bytes)
#define Y1_LDS  0           // bf16 [128 r][512 k], row stride 1024 B, off = ((c16^(r&7))<<4)
#define HH_LDS  131072      // bf16 [16 j][512 k], row stride 1024 B
#define LDS_SZ  147456      // 144 KB

__device__ __forceinline__ unsigned short f2bf(float f) {
    union { float f; unsigned u; } c; c.f = f;
    unsigned u = c.u;
    return (unsigned short)((u + 0x7fffu + ((u >> 16) & 1u)) >> 16);
}
__device__ __forceinline__ float bfbits2f(unsigned hi) {
    union { unsigned u; float f; } c; c.u = hi; return c.f;
}
__device__ __forceinline__ unsigned pk_bf16(float a, float b) {
#if __has_builtin(__builtin_amdgcn_cvt_pk_bf16_f32)
    bf16x2 p = __builtin_amdgcn_cvt_pk_bf16_f32(a, b);
    union { bf16x2 v; unsigned u; } c; c.v = p; return c.u;
#else
    return (unsigned)f2bf(a) | ((unsigned)f2bf(b) << 16);
#endif
}
// Y1 address: row r (0..127), 16-byte chunk c16 (0..63).
__device__ __forceinline__ int y1off(int r, int c16) {
    return r * 1024 + ((c16 ^ (r & 7)) << 4);
}

// static_for: fold over integral_constants (C++17)
template<class F, int... Is>
__device__ __forceinline__ void sf_impl(F& f, std::integer_sequence<int, Is...>) {
    (f(std::integral_constant<int, Is>{}), ...);
}
template<int N, class F>
__device__ __forceinline__ void static_for(F&& f) {
    sf_impl(f, std::make_integer_sequence<int, N>{});
}

// ---------------------------------------------------------------------------
// prep_pack: blocks 0..255 pack Wp2 into 32x32x16 B-frag layout
// ([kstep][ct][l]); 256..271 pack W1b (16x16x32 layout for Phase A);
// 272..279 fold k-consts (64 k each, 4-way e-split + LDS reduce);
// 280..283 fold A2/C2. All global reads coalesced. UNCHANGED.
// 32x32x16 B-frag: lane l holds B[k=kstep*16+(l>>5)*8+j][n=ct*32+(l&31)].
// 16x16x32 B-frag: lane l holds B[k=kb*32+(l>>4)*8+j][n=nt*16+(l&15)].
// ---------------------------------------------------------------------------
__global__ __launch_bounds__(256) void prep_pack_kernel(
    const float* __restrict__ Wsp,  const float* __restrict__ bsp,
    const float* __restrict__ Wp1,  const float* __restrict__ bp1,
    const float* __restrict__ gp1,  const float* __restrict__ btp1,
    const float* __restrict__ mp1,  const float* __restrict__ vp1,
    const float* __restrict__ Wp2,  const float* __restrict__ bp2,
    const float* __restrict__ gp2,  const float* __restrict__ btp2,
    const float* __restrict__ mp2,  const float* __restrict__ vp2,
    unsigned char* __restrict__ ws)
{
    __shared__ float tile[32 * 65];
    __shared__ float part[3][4][64];
    const int blk = blockIdx.x, t = threadIdx.x;

    if (blk < 272) {
        const float* src; int ncols, kb, ng;
        if (blk < 256) { kb = blk >> 4; ng = blk & 15; src = Wp2; ncols = 1024; }
        else { int b2 = blk - 256; kb = b2 >> 3; ng = b2 & 7; src = Wp1 + 64 * 512; ncols = 512; }
        const int k0 = kb * 32, n0 = ng * 64;
        #pragma unroll
        for (int it = 0; it < 2; ++it) {
            int c = t + it * 256;
            int r = c >> 4, c4 = c & 15;
            float4 v = *(const float4*)(src + (k0 + r) * ncols + n0 + c4 * 4);
            tile[r * 65 + c4 * 4 + 0] = v.x;
            tile[r * 65 + c4 * 4 + 1] = v.y;
            tile[r * 65 + c4 * 4 + 2] = v.z;
            tile[r * 65 + c4 * 4 + 3] = v.w;
        }
        __syncthreads();
        if (blk < 256) {
            const int l = t & 63, ch = (t >> 6) & 1, kh = t >> 7;
            const int nl = ch * 32 + (l & 31);
            const int kl = kh * 16 + ((l >> 5) & 1) * 8;
            uint4 o;
            o.x = pk_bf16(tile[(kl + 0) * 65 + nl], tile[(kl + 1) * 65 + nl]);
            o.y = pk_bf16(tile[(kl + 2) * 65 + nl], tile[(kl + 3) * 65 + nl]);
            o.z = pk_bf16(tile[(kl + 4) * 65 + nl], tile[(kl + 5) * 65 + nl]);
            o.w = pk_bf16(tile[(kl + 6) * 65 + nl], tile[(kl + 7) * 65 + nl]);
            const int kstep = kb * 2 + kh, ct = ng * 2 + ch;
            ((uint4*)(ws + BP2_OFF))[(kstep * 32 + ct) * 64 + l] = o;
        } else {
            int ntl = t >> 6, l = t & 63;
            int nl = ntl * 16 + (l & 15), kl = (l >> 4) * 8;
            uint4 o;
            o.x = pk_bf16(tile[(kl + 0) * 65 + nl], tile[(kl + 1) * 65 + nl]);
            o.y = pk_bf16(tile[(kl + 2) * 65 + nl], tile[(kl + 3) * 65 + nl]);
            o.z = pk_bf16(tile[(kl + 4) * 65 + nl], tile[(kl + 5) * 65 + nl]);
            o.w = pk_bf16(tile[(kl + 6) * 65 + nl], tile[(kl + 7) * 65 + nl]);
            ((uint4*)(ws + BP1_OFF))[((ng * 4 + ntl) * 2 + kb) * 64 + l] = o;
        }
    } else if (blk < 280) {
        const int kk = t & 63, eq = t >> 6;
        const int k = (blk - 272) * 64 + kk;
        float mx = 0.f, my = 0.f, cb = 0.f;
        #pragma unroll
        for (int e2 = 0; e2 < 16; ++e2) {
            int e = eq * 16 + e2;
            float wv = Wp1[e * 512 + k];
            mx = fmaf(Wsp[e],      wv, mx);
            my = fmaf(Wsp[64 + e], wv, my);
            cb = fmaf(bsp[e],      wv, cb);
        }
        part[0][eq][kk] = mx; part[1][eq][kk] = my; part[2][eq][kk] = cb;
        __syncthreads();
        if (t < 64) {
            const int k2 = (blk - 272) * 64 + t;
            float mxs = part[0][0][t] + part[0][1][t] + part[0][2][t] + part[0][3][t];
            float mys = part[1][0][t] + part[1][1][t] + part[1][2][t] + part[1][3][t];
            float cbs = part[2][0][t] + part[2][1][t] + part[2][2][t] + part[2][3][t];
            float a1 = gp1[k2] * rsqrtf(vp1[k2] + 1e-5f);
            ((float*)(ws + MX_OFF))[k2] = 0.05f * a1 * mxs;
            ((float*)(ws + MY_OFF))[k2] = 0.05f * a1 * mys;
            ((float*)(ws + CB_OFF))[k2] = 0.05f * a1 * cbs + (bp1[k2] - mp1[k2]) * a1 + btp1[k2];
            ((float*)(ws + SH_OFF))[k2] = 0.05f * a1;
        }
    } else {
        int n = (blk - 280) * 256 + t;
        float a = gp2[n] * rsqrtf(vp2[n] + 1e-5f);
        ((float*)(ws + A2_OFF))[n] = a;
        ((float*)(ws + C2_OFF))[n] = btp2[n] + (bp2[n] - mp2[n]) * a;
    }
}

// ---------------------------------------------------------------------------
// mm5 v23: WG = (scene s, i-half ih). 256 thr = 4 waves (1/SIMD).
// Phase A: HH[16x512] via 16 MFMA/wave (8 coltiles each).
// Phase B: construct Y1[128x512] bf16 (256 thr x 8 ii).
// Phase C: wave = 4rt x 4ct, 2 passes of 16 coltiles; static 64-step
//   schedule, A/B ring-2 (slot = G&1), counted waits; acc[4][4]=256 AGPR.
// ---------------------------------------------------------------------------
__global__ __launch_bounds__(256, 1) void mm5_kernel(
    const float* __restrict__ hst,
    const float* __restrict__ epos,
    const unsigned char* __restrict__ ws,
    float* __restrict__ out)
{
    __shared__ __align__(16) unsigned char smem[LDS_SZ];

    const int s   = blockIdx.x >> 1;     // 256 scenes
    const int ih  = blockIdx.x & 1;      // i-half
    const int tid = threadIdx.x;
    const int w    = tid >> 6;           // 0..3
    const int l    = tid & 63;
    const int quad = l >> 4;
    const int jl   = l & 15;

    // ---- Phase A: HH via MFMA (16x16x32); wave w -> k-cols w*128..+127 ----
    {
        union { unsigned u[4]; bf16x8 v; } afh[2];
        #pragma unroll
        for (int kb = 0; kb < 2; ++kb) {
            const float4* hp = (const float4*)(hst + (s * 16 + jl) * 64 + kb * 32 + quad * 8);
            float4 v0 = hp[0], v1 = hp[1];
            afh[kb].u[0] = pk_bf16(v0.x, v0.y);
            afh[kb].u[1] = pk_bf16(v0.z, v0.w);
            afh[kb].u[2] = pk_bf16(v1.x, v1.y);
            afh[kb].u[3] = pk_bf16(v1.z, v1.w);
        }
        const f32x4 fz = {0.f, 0.f, 0.f, 0.f};
        f32x4 acch[8] = {fz, fz, fz, fz, fz, fz, fz, fz};
        #pragma unroll
        for (int kb = 0; kb < 2; ++kb) {
            #pragma unroll
            for (int ct = 0; ct < 8; ++ct) {
                bf16x8 bfr = *(const bf16x8*)(ws + BP1_OFF + ((((w * 8 + ct) * 2 + kb) * 64 + l) << 4));
                acch[ct] = __builtin_amdgcn_mfma_f32_16x16x32_bf16(afh[kb].v, bfr, acch[ct], 0, 0, 0);
            }
        }
        const float* SHg = (const float*)(ws + SH_OFF);
        const float* CBg = (const float*)(ws + CB_OFF);
        #pragma unroll
        for (int ct = 0; ct < 8; ++ct) {
            int col = (w * 8 + ct) * 16 + jl;        // k index
            float sh = SHg[col], cb = CBg[col];
            #pragma unroll
            for (int reg = 0; reg < 4; ++reg) {
                int j = quad * 4 + reg;
                float hv = fmaf(acch[ct][reg], sh, cb);
                *(unsigned short*)(smem + HH_LDS + j * 1024 + col * 2) = f2bf(hv);
            }
        }
    }
    __syncthreads();

    // ---- Phase B: construct Y1[128x512] (bf16, swizzled); 8 ii/thread ----
    {
        const int j  = tid >> 4;           // 0..15
        const int kc = tid & 15;
        float rx[8], ry[8];
        float pjx = epos[s * 32 + j * 2], pjy = epos[s * 32 + j * 2 + 1];
        #pragma unroll
        for (int ii = 0; ii < 8; ++ii) {
            int ig_ = ih * 8 + ii;
            rx[ii] = pjx - epos[s * 32 + ig_ * 2];
            ry[ii] = pjy - epos[s * 32 + ig_ * 2 + 1];
        }
        const f32x2 zero2 = {0.f, 0.f};
        #pragma unroll
        for (int kk = 0; kk < 4; ++kk) {
            int c16 = kk * 16 + kc;
            int k = c16 * 8;
            uint4 hh8 = *(const uint4*)(smem + HH_LDS + j * 1024 + k * 2);
            f32x4 mx0 = *(const f32x4*)(ws + MX_OFF + k * 4);
            f32x4 mx1 = *(const f32x4*)(ws + MX_OFF + k * 4 + 16);
            f32x4 my0 = *(const f32x4*)(ws + MY_OFF + k * 4);
            f32x4 my1 = *(const f32x4*)(ws + MY_OFF + k * 4 + 16);
            f32x2 mxp[4] = { {mx0[0],mx0[1]}, {mx0[2],mx0[3]}, {mx1[0],mx1[1]}, {mx1[2],mx1[3]} };
            f32x2 myp[4] = { {my0[0],my0[1]}, {my0[2],my0[3]}, {my1[0],my1[1]}, {my1[2],my1[3]} };
            f32x2 hhp[4];
            hhp[0][0] = bfbits2f(hh8.x << 16); hhp[0][1] = bfbits2f(hh8.x & 0xffff0000u);
            hhp[1][0] = bfbits2f(hh8.y << 16); hhp[1][1] = bfbits2f(hh8.y & 0xffff0000u);
            hhp[2][0] = bfbits2f(hh8.z << 16); hhp[2][1] = bfbits2f(hh8.z & 0xffff0000u);
            hhp[3][0] = bfbits2f(hh8.w << 16); hhp[3][1] = bfbits2f(hh8.w & 0xffff0000u);
            #pragma unroll
            for (int ii = 0; ii < 8; ++ii) {
                f32x2 rx2 = { rx[ii], rx[ii] };
                f32x2 ry2 = { ry[ii], ry[ii] };
                uint4 o;
                unsigned uu[4];
                #pragma unroll
                for (int p = 0; p < 4; ++p) {
                    f32x2 tt = __builtin_elementwise_fma(ry2, myp[p], hhp[p]);
                    tt = __builtin_elementwise_fma(rx2, mxp[p], tt);
                    tt = __builtin_elementwise_max(tt, zero2);
                    uu[p] = pk_bf16(tt[0], tt[1]);
                }
                o.x = uu[0]; o.y = uu[1]; o.z = uu[2]; o.w = uu[3];
                int r = ii * 16 + j;
                *(uint4*)(smem + Y1_LDS + y1off(r, c16)) = o;
            }
        }
    }
    __syncthreads();

    // ---- Phase C: 32x32x16 GEMM, 4 waves, 4rt x 4ct per wave ----
    {
        const int lane31 = l & 31;           // A-frag m, C col
        const int hi = l >> 5;               // k-half; C row group
        const int sr = lane31 & 7;
        const float* A2 = (const float*)(ws + A2_OFF);
        const float* C2 = (const float*)(ws + C2_OFF);

        // A addr(rt, k) = (av[rt] + (k>>2)*128) ^ ((k&3)<<5)
        int av[4];
        #pragma unroll
        for (int rt = 0; rt < 4; ++rt)
            av[rt] = Y1_LDS + (rt * 32 + lane31) * 1024 + ((hi ^ sr) << 4);

        // B addr(pass, k, c) = bp + pass*16384 + k*32768 + c*1024 (c 0..3)
        const unsigned char* bp = ws + BP2_OFF + ((w * 4) << 10) + (l << 4);

        const f32x16 fz16 = {0.f,0.f,0.f,0.f,0.f,0.f,0.f,0.f,
                             0.f,0.f,0.f,0.f,0.f,0.f,0.f,0.f};
        f32x16 acc[4][4];                    // 256 AGPR (1 wave/SIMD budget)
        bf16x8 ar[2][4];                     // A ring-2, slot = G&1: [slot][rt]
        bf16x8 br[2][4];                     // B ring-2, slot = G&1: [slot][c]

        #pragma unroll
        for (int rt = 0; rt < 4; ++rt)
            #pragma unroll
            for (int c = 0; c < 4; ++c) acc[rt][c] = fz16;

        // epilogue: bn2 + relu, maxpool over j, store fp32. 8 loads + 16 st.
        // C/D 32x32: col = lane&31, row = (reg&3)+8*(reg>>2)+4*hi (+16 hg=1).
        auto epilogue = [&](int pass) {
            #pragma unroll
            for (int c = 0; c < 4; ++c) {
                const int col = (pass * 16 + w * 4 + c) * 32 + lane31;
                const float a2 = A2[col], c2 = C2[col];
                #pragma unroll
                for (int rt = 0; rt < 4; ++rt) {
                    float mv[2];
                    #pragma unroll
                    for (int hg = 0; hg < 2; ++hg) {
                        float v0 = fmaxf(fmaf(acc[rt][c][hg * 8 + 0], a2, c2), 0.f);
                        float v1 = fmaxf(fmaf(acc[rt][c][hg * 8 + 1], a2, c2), 0.f);
                        float v2 = fmaxf(fmaf(acc[rt][c][hg * 8 + 2], a2, c2), 0.f);
                        float v3 = fmaxf(fmaf(acc[rt][c][hg * 8 + 3], a2, c2), 0.f);
                        float v4 = fmaxf(fmaf(acc[rt][c][hg * 8 + 4], a2, c2), 0.f);
                        float v5 = fmaxf(fmaf(acc[rt][c][hg * 8 + 5], a2, c2), 0.f);
                        float v6 = fmaxf(fmaf(acc[rt][c][hg * 8 + 6], a2, c2), 0.f);
                        float v7 = fmaxf(fmaf(acc[rt][c][hg * 8 + 7], a2, c2), 0.f);
                        float m = fmaxf(fmaxf(fmaxf(v0, v1), fmaxf(v2, v3)),
                                        fmaxf(fmaxf(v4, v5), fmaxf(v6, v7)));
                        mv[hg] = fmaxf(m, __shfl_xor(m, 32, 64));
                    }
                    const int iloc = rt * 2 + hi;      // hi=0 even i, hi=1 odd
                    const float vout = hi ? mv[1] : mv[0];
                    const int orow = s * 16 + ih * 8 + iloc;
                    __builtin_nontemporal_store(vout, &out[orow * 1024 + col]);
                }
            }
        };

        // issue loads for global step GN: 4 B (cached) + 4 A ds_reads
        auto issueG = [&](auto Gc) {
            constexpr int GN = decltype(Gc)::value;
            constexpr int pn = GN >> 5, kn = GN & 31, sl = GN & 1;
            const unsigned char* b = bp + (pn * 16384 + kn * 32768);
            #pragma unroll
            for (int c = 0; c < 4; ++c)
                br[sl][c] = *(const bf16x8*)(b + c * 1024);
            constexpr int add = (kn >> 2) * 128;
            constexpr int xr  = (kn & 3) << 5;
            #pragma unroll
            for (int rt = 0; rt < 4; ++rt)
                ar[sl][rt] = *(const bf16x8*)(smem + ((av[rt] + add) ^ xr));
        };

        auto stepG = [&](auto Gc) {
            constexpr int G = decltype(Gc)::value;
            if constexpr (G + 1 <= 63)
                issueG(std::integral_constant<int, G + 1>{});
            // waits (in-order vmcnt retire):
            //   steady: B lead-1 -> vmcnt(4); A lead-1 -> lgkmcnt(4).
            //   G=32: order B32(4), epi(8 ld + 16 st), B33(4) -> retire B32
            //         at <= 28 outstanding -> vmcnt(28). A32 already
            //         drained by epilogue's shfl lgkm waits (in-order).
            //   G=63: full drain.
            if constexpr (G == 32)
                asm volatile("s_waitcnt vmcnt(28) lgkmcnt(4)" ::: "memory");
            else if constexpr (G == 63)
                asm volatile("s_waitcnt vmcnt(0) lgkmcnt(0)" ::: "memory");
            else
                asm volatile("s_waitcnt vmcnt(4) lgkmcnt(4)" ::: "memory");
            __builtin_amdgcn_sched_barrier(0);
            constexpr int sl = G & 1;
            #pragma unroll
            for (int c = 0; c < 4; ++c)
                #pragma unroll
                for (int rt = 0; rt < 4; ++rt)
                    acc[rt][c] = __builtin_amdgcn_mfma_f32_32x32x16_bf16(
                        ar[sl][rt], br[sl][c], acc[rt][c], 0, 0, 0);
        };

        // prologue: G=0's loads
        issueG(std::integral_constant<int, 0>{});

        static_for<32>(stepG);                          // G = 0..31 (pass 0)
        __builtin_amdgcn_sched_barrier(0);
        epilogue(0);
        #pragma unroll
        for (int rt = 0; rt < 4; ++rt)
            #pragma unroll
            for (int c = 0; c < 4; ++c) acc[rt][c] = fz16;
        __builtin_amdgcn_sched_barrier(0);
        static_for<32>([&](auto kc) {                   // G = 32..63 (pass 1)
            stepG(std::integral_constant<int, decltype(kc)::value + 32>{});
        });
        __builtin_amdgcn_sched_barrier(0);
        epilogue(1);
    }
}

extern "C" void kernel_launch(void* const* d_in, const int* in_sizes, int n_in,
                              void* d_out, int out_size, void* d_ws, size_t ws_size,
                              hipStream_t stream) {
    const float* hst  = (const float*)d_in[0];
    const float* epos = (const float*)d_in[1];
    const float* Wsp  = (const float*)d_in[4];
    const float* bsp  = (const float*)d_in[5];
    const float* Wp1  = (const float*)d_in[20];
    const float* bp1  = (const float*)d_in[21];
    const float* gp1  = (const float*)d_in[22];
    const float* btp1 = (const float*)d_in[23];
    const float* mp1  = (const float*)d_in[24];
    const float* vp1  = (const float*)d_in[25];
    const float* Wp2  = (const float*)d_in[26];
    const float* bp2  = (const float*)d_in[27];
    const float* gp2  = (const float*)d_in[28];
    const float* btp2 = (const float*)d_in[29];
    const float* mp2  = (const float*)d_in[30];
    const float* vp2  = (const float*)d_in[31];
    unsigned char* ws = (unsigned char*)d_ws;
    float* out = (float*)d_out;

    // 256 (Wp2 pack) + 16 (W1b pack) + 8 (k-consts) + 4 (A2/C2) = 284 blocks
    prep_pack_kernel<<<284, 256, 0, stream>>>(Wsp, bsp, Wp1, bp1, gp1, btp1, mp1, vp1,
                                              Wp2, bp2, gp2, btp2, mp2, vp2, ws);
    // 256 scenes x 2 i-halves, 256 threads (4 waves, 1/SIMD)
    mm5_kernel<<<512, 256, 0, stream>>>(hst, epos, ws, out);
}